// Round 1
// baseline (32.103 us; speedup 1.0000x reference)
//
#include <hip/hip_runtime.h>

#define NBATCH 1024
#define NELEC  64
#define NBAS   256
#define NORB   128
#define RPB    8   // electron-rows per block

__global__ __launch_bounds__(256, 4) void ao_kernel(
    const float* __restrict__ inp,            // [NBATCH*NELEC, 3]
    const float* __restrict__ atom_coords,    // [16, 3]
    const float* __restrict__ bas_exp,        // [NBAS]
    const float* __restrict__ bas_coeffs,     // [NBAS]
    const float* __restrict__ norm_cst,       // [NBAS]
    const int*   __restrict__ bas_l,          // [NBAS]
    const int*   __restrict__ bas_m,          // [NBAS]
    const int*   __restrict__ bas_atom_index, // [NBAS]
    const int*   __restrict__ index_ctr,      // [NBAS] sorted
    float* __restrict__ out)                  // [NBATCH*NELEC, NORB]
{
    __shared__ float s_vals[RPB][NBAS];   // 8 KB
    __shared__ int   s_idx[NBAS];
    __shared__ int   s_start[NORB + 1];

    const int tid  = threadIdx.x;
    const int j    = tid;                   // basis index, fixed per thread
    const int row0 = blockIdx.x * RPB;

    // per-thread basis parameters (coalesced loads, loop-invariant)
    float ex = bas_exp[j];
    float cc = norm_cst[j] * bas_coeffs[j];
    int   l  = bas_l[j];
    int   m  = bas_m[j];
    int   ai = bas_atom_index[j];
    float cx = atom_coords[ai * 3 + 0];
    float cy = atom_coords[ai * 3 + 1];
    float cz = atom_coords[ai * 3 + 2];
    s_idx[j] = index_ctr[j];

    // fold the spherical-harmonic constant into cc; r^l cancels /r, /r^2
    const float C0 = 0.2820948f, C1 = 0.4886025f, C2XY = 1.0925484f,
                C2Z2 = 0.31539156f, C2D = 0.5462742f;
    float C = (l == 0) ? C0 : (l == 1) ? C1
            : (m == 0) ? C2Z2 : (m == 2) ? C2D : C2XY;
    cc *= C;
    const float nex = -ex * 1.4426950408889634f;  // fold log2(e) for exp2

    __syncthreads();   // s_idx visible
    if (tid <= NORB) { // lower_bound(tid) over sorted s_idx -> segment starts
        int lo = 0, hi = NBAS;
        while (lo < hi) {
            int mid = (lo + hi) >> 1;
            if (s_idx[mid] < tid) lo = mid + 1; else hi = mid;
        }
        s_start[tid] = lo;
    }

    // phase 1: each thread evaluates its basis function for RPB rows
    #pragma unroll
    for (int r = 0; r < RPB; ++r) {
        // wave-uniform addresses -> scalar loads
        float px = inp[(row0 + r) * 3 + 0];
        float py = inp[(row0 + r) * 3 + 1];
        float pz = inp[(row0 + r) * 3 + 2];
        float x = px - cx, y = py - cy, z = pz - cz;
        float xx = x * x, yy = y * y, zz = z * z;
        float r2 = xx + yy + zz;
        float s1 = (m == -1) ? y : (m == 0) ? z : x;                 // l=1
        float q  = (m == -2) ? x * y : (m == -1) ? y * z             // l=2
                 : (m == 0)  ? fmaf(3.0f, zz, -r2)
                 : (m == 1)  ? z * x : (xx - yy);
        float P  = (l == 0) ? 1.0f : (l == 1) ? s1 : q;
        s_vals[r][j] = cc * __builtin_exp2f(nex * r2) * P;
    }
    __syncthreads();

    // phase 2: deterministic segment-sum; thread t -> row (t>>5), orbitals 4*(t&31)..+3
    const int rr = tid >> 5;
    const int ob = (tid & 31) << 2;
    float acc[4] = {0.f, 0.f, 0.f, 0.f};
    #pragma unroll
    for (int k = 0; k < 4; ++k) {
        int o = ob + k;
        int e = s_start[o + 1];
        for (int jj = s_start[o]; jj < e; ++jj) acc[k] += s_vals[rr][jj];
    }
    float4 v = make_float4(acc[0], acc[1], acc[2], acc[3]);
    *reinterpret_cast<float4*>(&out[(size_t)(row0 + rr) * NORB + ob]) = v;
}

extern "C" void kernel_launch(void* const* d_in, const int* in_sizes, int n_in,
                              void* d_out, int out_size, void* d_ws, size_t ws_size,
                              hipStream_t stream) {
    const float* inp   = (const float*)d_in[0];
    const float* atomc = (const float*)d_in[1];
    const float* bexp  = (const float*)d_in[2];
    const float* bcoef = (const float*)d_in[3];
    const float* bnorm = (const float*)d_in[4];
    // d_in[5] = bas_n (float) — redundant with bas_l, unused
    const int* bl   = (const int*)d_in[6];
    const int* bm   = (const int*)d_in[7];
    const int* bai  = (const int*)d_in[8];
    const int* ictr = (const int*)d_in[9];
    float* out = (float*)d_out;

    dim3 grid((NBATCH * NELEC) / RPB);   // 8192 blocks
    dim3 block(256);
    hipLaunchKernelGGL(ao_kernel, grid, block, 0, stream,
                       inp, atomc, bexp, bcoef, bnorm, bl, bm, bai, ictr, out);
}

// Round 2
// 25.552 us; speedup vs baseline: 1.2564x; 1.2564x over previous
//
#include <hip/hip_runtime.h>

#define NBATCH 1024
#define NELEC  64
#define NBAS   256
#define NORB   128
#define RPB    8   // electron-rows per block

__global__ __launch_bounds__(256, 4) void ao_kernel(
    const float* __restrict__ inp,            // [NBATCH*NELEC, 3]
    const float* __restrict__ atom_coords,    // [16, 3]
    const float* __restrict__ bas_exp,        // [NBAS]
    const float* __restrict__ bas_coeffs,     // [NBAS]
    const float* __restrict__ norm_cst,       // [NBAS]
    const int*   __restrict__ bas_l,          // [NBAS]
    const int*   __restrict__ bas_m,          // [NBAS]
    const int*   __restrict__ bas_atom_index, // [NBAS]
    const int*   __restrict__ index_ctr,      // [NBAS] sorted
    float* __restrict__ out)                  // [NBATCH*NELEC, NORB]
{
    __shared__ __align__(16) float s_vals[RPB][NBAS];   // vals, then in-place prefix
    __shared__ int s_idx[NBAS];
    __shared__ int s_start[NORB + 1];

    const int tid  = threadIdx.x;
    const int row0 = blockIdx.x * RPB;

    // ---- per-thread basis parameters (one basis per thread) ----
    float ex = bas_exp[tid];
    float cc = norm_cst[tid] * bas_coeffs[tid];
    int   l  = bas_l[tid];
    int   m  = bas_m[tid];
    int   ai = bas_atom_index[tid];
    float cx = atom_coords[ai * 3 + 0];
    float cy = atom_coords[ai * 3 + 1];
    float cz = atom_coords[ai * 3 + 2];
    s_idx[tid] = index_ctr[tid];

    // fold spherical constant into cc (r^l cancels the 1/r, 1/r^2 factors)
    const float C0 = 0.2820948f, C1 = 0.4886025f, C2XY = 1.0925484f,
                C2Z2 = 0.31539156f, C2D = 0.5462742f;
    float C = (l == 0) ? C0 : (l == 1) ? C1
            : (m == 0) ? C2Z2 : (m == 2) ? C2D : C2XY;
    cc *= C;
    const float nex = -ex * 1.4426950408889634f;  // fold log2(e) for v_exp_f32

    // angular part as bilinear form: P = (a.[x,y,z,1]) * (b.[x,y,z,1]) + c9*r2
    float a0=0.f,a1=0.f,a2=0.f,a3=0.f, b0=0.f,b1=0.f,b2=0.f,b3=0.f, c9=0.f;
    if (l == 0)            { a3 = 1.f; b3 = 1.f; }
    else if (l == 1) {
        if      (m == -1)  { a1 = 1.f; b3 = 1.f; }
        else if (m ==  0)  { a2 = 1.f; b3 = 1.f; }
        else               { a0 = 1.f; b3 = 1.f; }
    } else {
        if      (m == -2)  { a0 = 1.f; b1 = 1.f; }                  // xy
        else if (m == -1)  { a1 = 1.f; b2 = 1.f; }                  // yz
        else if (m ==  0)  { a2 = 1.f; b2 = 3.f; c9 = -1.f; }       // 3z^2 - r^2
        else if (m ==  1)  { a2 = 1.f; b0 = 1.f; }                  // zx
        else               { a0 = 1.f; a1 = 1.f; b0 = 1.f; b1 = -1.f; } // x^2-y^2
    }

    __syncthreads();   // s_idx visible
    if (tid <= NORB) { // lower_bound over sorted s_idx -> segment starts
        int lo = 0, hi = NBAS;
        while (lo < hi) {
            int mid = (lo + hi) >> 1;
            if (s_idx[mid] < tid) lo = mid + 1; else hi = mid;
        }
        s_start[tid] = lo;
    }

    // ---- phase 1: evaluate basis tid for RPB rows ----
    #pragma unroll
    for (int r = 0; r < RPB; ++r) {
        float px = inp[(row0 + r) * 3 + 0];   // wave-uniform -> scalar loads
        float py = inp[(row0 + r) * 3 + 1];
        float pz = inp[(row0 + r) * 3 + 2];
        float x = px - cx, y = py - cy, z = pz - cz;
        float r2 = fmaf(x, x, fmaf(y, y, z * z));
        float A  = fmaf(a0, x, fmaf(a1, y, fmaf(a2, z, a3)));
        float B  = fmaf(b0, x, fmaf(b1, y, fmaf(b2, z, b3)));
        float P  = fmaf(c9, r2, A * B);
        s_vals[r][tid] = cc * __builtin_exp2f(nex * r2) * P;
    }
    __syncthreads();

    // ---- phase 2: in-place inclusive prefix scan of each row (wave per 2 rows) ----
    const int wv = tid >> 6, ln = tid & 63;
    #pragma unroll
    for (int rs = 0; rs < 2; ++rs) {
        const int r = wv * 2 + rs;
        float4 v = *reinterpret_cast<const float4*>(&s_vals[r][ln << 2]);
        float e0 = v.x;
        float e1 = e0 + v.y;
        float e2 = e1 + v.z;
        float e3 = e2 + v.w;
        float s = e3;                       // wave inclusive scan of lane sums
        #pragma unroll
        for (int off = 1; off < 64; off <<= 1) {
            float t = __shfl_up(s, off);
            if (ln >= off) s += t;
        }
        float excl = s - e3;                // exclusive prefix for this lane
        *reinterpret_cast<float4*>(&s_vals[r][ln << 2]) =
            make_float4(e0 + excl, e1 + excl, e2 + excl, e3 + excl);
    }
    __syncthreads();

    // ---- phase 3: out[o] = P[start[o+1]-1] - P[start[o]-1]; 4 orbitals/thread ----
    const int rr = tid >> 5;
    const int ob = (tid & 31) << 2;
    int st[5];
    #pragma unroll
    for (int k = 0; k < 5; ++k) st[k] = s_start[ob + k];
    float p[5];
    #pragma unroll
    for (int k = 0; k < 5; ++k) {
        int idx = st[k] - 1;
        float v = s_vals[rr][idx < 0 ? 0 : idx];   // clamped read, independent loads
        p[k] = (st[k] > 0) ? v : 0.0f;
    }
    float4 o4 = make_float4(p[1] - p[0], p[2] - p[1], p[3] - p[2], p[4] - p[3]);
    *reinterpret_cast<float4*>(&out[(size_t)(row0 + rr) * NORB + ob]) = o4;
}

extern "C" void kernel_launch(void* const* d_in, const int* in_sizes, int n_in,
                              void* d_out, int out_size, void* d_ws, size_t ws_size,
                              hipStream_t stream) {
    const float* inp   = (const float*)d_in[0];
    const float* atomc = (const float*)d_in[1];
    const float* bexp  = (const float*)d_in[2];
    const float* bcoef = (const float*)d_in[3];
    const float* bnorm = (const float*)d_in[4];
    // d_in[5] = bas_n (float) — redundant with bas_l, unused
    const int* bl   = (const int*)d_in[6];
    const int* bm   = (const int*)d_in[7];
    const int* bai  = (const int*)d_in[8];
    const int* ictr = (const int*)d_in[9];
    float* out = (float*)d_out;

    dim3 grid((NBATCH * NELEC) / RPB);   // 8192 blocks
    dim3 block(256);
    hipLaunchKernelGGL(ao_kernel, grid, block, 0, stream,
                       inp, atomc, bexp, bcoef, bnorm, bl, bm, bai, ictr, out);
}